// Round 10
// baseline (1628.158 us; speedup 1.0000x reference)
//
#include <hip/hip_runtime.h>
#include <hip/hip_fp16.h>
#include <math.h>

// Problem constants: B=4, C=256, H=W=64 -> HW=4096
#define HW 4096
#define NC 256
#define NB 4
#define EPSF 1e-5f
#define TEN (NB * HW * NC)  // elements per output tensor = 4194304

typedef _Float16 half8 __attribute__((ext_vector_type(8)));
typedef _Float16 half4v __attribute__((ext_vector_type(4)));
typedef float f32x4 __attribute__((ext_vector_type(4)));
typedef unsigned int u32;

// ws layout (bytes):
//  [0, 16K)   stats f32: meanC[1024], rstdC[1024], meanS[1024], rstdS[1024]
//  QF : f16 [b][pix][256]  (pixel-major)
//  KF : f16 [b][pix][256]  (pixel-major)
//  VF : f16 [b][ch][4096]  (channel-major)
#define STATS_BYTES (4096 * 4)
#define QF_OFF  (STATS_BYTES)
#define KF_OFF  (QF_OFF + TEN * 2)
#define VF_OFF  (KF_OFF + TEN * 2)

// async global->LDS, 16B/lane; LDS dest = wave-uniform base + lane*16
typedef const __attribute__((address_space(1))) void* gas_vp;
typedef __attribute__((address_space(3))) void* las_vp;
__device__ __forceinline__ void gload_lds16(const void* g, void* l) {
  __builtin_amdgcn_global_load_lds((gas_vp)g, (las_vp)l, 16, 0, 0);
}

// ---------------------------------------------------------------------------
// Kernel 1: per-(b,c) mean and rstd for content and style.
// ---------------------------------------------------------------------------
__global__ __launch_bounds__(256) void stats_kernel(
    const float* __restrict__ content, const float* __restrict__ style,
    float* __restrict__ ws) {
  int bc = blockIdx.x;
  int t = threadIdx.x;
  const float* src = (bc < 1024 ? content : style) + (size_t)(bc & 1023) * HW;
  const float4* s4 = (const float4*)src;
  float sum = 0.f, ss = 0.f;
#pragma unroll
  for (int n = 0; n < 4; ++n) {
    float4 v = s4[t + n * 256];
    sum += v.x + v.y + v.z + v.w;
    ss += v.x * v.x + v.y * v.y + v.z * v.z + v.w * v.w;
  }
#pragma unroll
  for (int m = 1; m < 64; m <<= 1) {
    sum += __shfl_xor(sum, m, 64);
    ss += __shfl_xor(ss, m, 64);
  }
  __shared__ float redS[4], redQ[4];
  int w = t >> 6;
  if ((t & 63) == 0) { redS[w] = sum; redQ[w] = ss; }
  __syncthreads();
  if (t == 0) {
    float S = redS[0] + redS[1] + redS[2] + redS[3];
    float Q2 = redQ[0] + redQ[1] + redQ[2] + redQ[3];
    float mean = S * (1.0f / HW);
    float var = (Q2 - S * mean) * (1.0f / (HW - 1));
    float rstd = rsqrtf(var + EPSF);
    float* meanArr = ws + (bc < 1024 ? 0 : 2048);
    float* rstdArr = meanArr + 1024;
    meanArr[bc & 1023] = mean;
    rstdArr[bc & 1023] = rstd;
  }
}

// ---------------------------------------------------------------------------
// Kernel 2: fused normalize + 1x1 conv; f16 outputs (V only; V^2 in attn).
// ---------------------------------------------------------------------------
__global__ __launch_bounds__(256) void proj_kernel(
    const float* __restrict__ content, const float* __restrict__ style,
    const float* __restrict__ Wf, const float* __restrict__ bf,
    const float* __restrict__ Wg, const float* __restrict__ bg,
    const float* __restrict__ Wh, const float* __restrict__ bh,
    char* __restrict__ wsb) {
  float* ws = (float*)wsb;
  int pt = blockIdx.x;
  int ot = blockIdx.y;
  int z = blockIdx.z;
  int tensor = z >> 2, b = z & 3;

  const float* X; const float* Wm; const float* bias;
  const float* meanA = nullptr; const float* rstdA = nullptr;
  if (tensor == 0)      { X = content; Wm = Wf; bias = bf; meanA = ws;        rstdA = ws + 1024; }
  else if (tensor == 1) { X = style;   Wm = Wg; bias = bg; meanA = ws + 2048; rstdA = ws + 3072; }
  else                  { X = style;   Wm = Wh; bias = bh; }

  __shared__ float Xs[32 * 132];
  __shared__ float Wt[32 * 68];

  int t = threadIdx.x;
  int p0 = pt * 128, o0 = ot * 64;
  int o_base = (t >> 4) * 4;
  int p_base = (t & 15) * 8;

  float bb[4];
  { float4 b4 = *(const float4*)&bias[o0 + o_base];
    bb[0] = b4.x; bb[1] = b4.y; bb[2] = b4.z; bb[3] = b4.w; }
  float acc[4][8];
#pragma unroll
  for (int oo = 0; oo < 4; ++oo)
#pragma unroll
    for (int pp = 0; pp < 8; ++pp) acc[oo][pp] = bb[oo];

  const float4* X4 = (const float4*)X;
  const float4* Wm4 = (const float4*)Wm;

  for (int kc = 0; kc < 8; ++kc) {
    int k0 = kc * 32;
    __syncthreads();
#pragma unroll
    for (int n = 0; n < 4; ++n) {
      int f = t + n * 256;
      int kk = f >> 5, p4 = f & 31;
      float4 v = X4[(size_t)(b * NC + k0 + kk) * (HW / 4) + (p0 / 4) + p4];
      if (tensor < 2) {
        float mC = meanA[b * NC + k0 + kk], rC = rstdA[b * NC + k0 + kk];
        v.x = (v.x - mC) * rC; v.y = (v.y - mC) * rC;
        v.z = (v.z - mC) * rC; v.w = (v.w - mC) * rC;
      }
      *(float4*)&Xs[kk * 132 + p4 * 4] = v;
    }
#pragma unroll
    for (int n = 0; n < 2; ++n) {
      int f = t + n * 256;
      int o = f >> 3, k4 = f & 7;
      float4 v = Wm4[(size_t)(o0 + o) * (NC / 4) + kc * 8 + k4];
      Wt[(k4 * 4 + 0) * 68 + o] = v.x;
      Wt[(k4 * 4 + 1) * 68 + o] = v.y;
      Wt[(k4 * 4 + 2) * 68 + o] = v.z;
      Wt[(k4 * 4 + 3) * 68 + o] = v.w;
    }
    __syncthreads();
#pragma unroll
    for (int kk = 0; kk < 32; ++kk) {
      float4 w4 = *(float4*)&Wt[kk * 68 + o_base];
      float4 xa = *(float4*)&Xs[kk * 132 + p_base];
      float4 xb = *(float4*)&Xs[kk * 132 + p_base + 4];
      float wv[4] = {w4.x, w4.y, w4.z, w4.w};
      float xv[8] = {xa.x, xa.y, xa.z, xa.w, xb.x, xb.y, xb.z, xb.w};
#pragma unroll
      for (int oo = 0; oo < 4; ++oo)
#pragma unroll
        for (int pp = 0; pp < 8; ++pp)
          acc[oo][pp] = fmaf(wv[oo], xv[pp], acc[oo][pp]);
    }
  }

  if (tensor < 2) {
    _Float16* dst = (_Float16*)(wsb + (tensor == 0 ? QF_OFF : KF_OFF));
#pragma unroll
    for (int pp = 0; pp < 8; ++pp) {
      half4v h;
      h[0] = (_Float16)acc[0][pp]; h[1] = (_Float16)acc[1][pp];
      h[2] = (_Float16)acc[2][pp]; h[3] = (_Float16)acc[3][pp];
      *(half4v*)&dst[((size_t)(b * HW) + p0 + p_base + pp) * 256 + o0 + o_base] = h;
    }
  } else {
    _Float16* dV = (_Float16*)(wsb + VF_OFF);
#pragma unroll
    for (int oo = 0; oo < 4; ++oo) {
      int ch = o0 + o_base + oo;
      half8 hv;
#pragma unroll
      for (int pp = 0; pp < 8; ++pp) hv[pp] = (_Float16)acc[oo][pp];
      size_t base = ((size_t)(b * NC) + ch) * HW + p0 + p_base;
      *(half8*)&dV[base] = hv;
    }
  }
}

// ---------------------------------------------------------------------------
// Kernel 3: flash attention, single pass, defer-max — ROUND-10: S-pipelined.
// r8 (618us, best) was chain-bound: QK->softmax->exchange->PV->barrier is
// one serial dependency per tile; MFMA and VALU pipes never overlap within
// a wave (r9's A/B: +TLP via 4x QK dup = net loss; the chain is the wall).
// This round pipelines S across tiles: each iteration computes QK(t+1)
// (fresh regs, from the LDS buffer staged last iteration) while
// softmax(t)+PV(t) run on the SAVED S — softmax has no dep on QK(t+1), so
// the VALU work issues under the 16 QK MFMAs (m114 co-schedule). The
// vmcnt+barrier moves to iteration top (before the only LDS reader),
// where gll K(t+1) has had a full iteration (~700cy) to land.
// Numerics BIT-IDENTICAL to r8 (same ops per (q,ch), same order).
// All r8 pieces verbatim: dbuf K via gll pre-swizzled source, swapped QK,
// defer-max + alpha redistribution (r8 fix), 12-shfl P exchange, V direct
// L2 (half before QK, half after), V^2 hi/lo in-register, epilogue.
// Grid 512 (2 blocks/CU); XCD pin b = (bid&7)>>1.
// ---------------------------------------------------------------------------
__global__ __launch_bounds__(256, 3) void attn_kernel(
    char* __restrict__ wsb, const float* __restrict__ content,
    float* __restrict__ dout) {
  const _Float16* Qf = (const _Float16*)(wsb + QF_OFF);
  const _Float16* Kf = (const _Float16*)(wsb + KF_OFF);
  const _Float16* Vf = (const _Float16*)(wsb + VF_OFF);
  const float* meanC = (const float*)wsb;
  const float* rstdC = meanC + 1024;

  int raw = blockIdx.x;                      // 0..511
  int xcd = raw & 7;
  int b = xcd >> 1;
  int qt = ((raw >> 3) << 1) | (xcd & 1);    // 0..127, bijective
  int q0 = qt * 32;

  int t = threadIdx.x;
  int lane = t & 63;
  int w = t >> 6;     // 0..3
  int qh = w >> 1;    // 0..1: which 16 queries
  int chh = w & 1;    // 0..1: which 128 channels
  int ml = lane & 15;
  int kg4 = lane >> 4;
  int lo = kg4 & 1, hi = kg4 >> 1;

  __shared__ int4 smem[2048];                // 32 KB: two 16 KB K buffers
  _Float16* Kt0h = (_Float16*)smem;
  _Float16* Kt1h = (_Float16*)(smem + 1024);

  // ---- Q B-frags: 16 queries x 256 ch per wave (32 VGPRs) ----
  half8 Qb[8];
#pragma unroll
  for (int ks = 0; ks < 8; ++ks) {
    size_t off = ((size_t)(b * HW) + q0 + qh * 16 + ml) * 256 + ks * 32 + kg4 * 8;
    Qb[ks] = *(const half8*)(Qf + off);
  }

  f32x4 accm[8], accs[8];
#pragma unroll
  for (int nt = 0; nt < 8; ++nt) {
    accm[nt] = (f32x4){0.f, 0.f, 0.f, 0.f};
    accs[nt] = (f32x4){0.f, 0.f, 0.f, 0.f};
  }
  float mrun = -INFINITY;   // per-lane state for q = ml (uniform across kg4)
  float lrun = 0.f;         // per-lane partial (this lane's 8 key slots)

  const int4* Kg = (const int4*)(Kf + (size_t)b * HW * 256);  // [key][32 gran]
  const int4* Vg = (const int4*)(Vf + (size_t)b * NC * HW);   // [ch][512 gran]
  int vrow = chh * 128 + ml;

  // K staging source pre-swizzle (r4-r8-proven): LDS slot s = c*32+(key^c);
  // chunk n=w*4+j covers slots n*64+lane; src gran = (l31^c)*32+c.
  int ksrc[4];
  {
    int l5 = lane >> 5;
    int l31 = lane & 31;
#pragma unroll
    for (int j = 0; j < 4; ++j) {
      int c = (w * 4 + j) * 2 + l5;
      ksrc[j] = (l31 ^ c) * 32 + c;  // + kt*1024
    }
  }

  // ---- prologue: K(0)->buf0 (waited), K(1)->buf1 (in flight), QK(0) ----
#pragma unroll
  for (int j = 0; j < 4; ++j)
    gload_lds16(Kg + (size_t)ksrc[j], smem + (w * 4 + j) * 64);
  asm volatile("s_waitcnt vmcnt(0)" ::: "memory");
  __builtin_amdgcn_s_barrier();
#pragma unroll
  for (int j = 0; j < 4; ++j)
    gload_lds16(Kg + (size_t)(1024 + ksrc[j]), smem + 1024 + (w * 4 + j) * 64);

  f32x4 S0 = (f32x4){0.f, 0.f, 0.f, 0.f};
  f32x4 S1 = (f32x4){0.f, 0.f, 0.f, 0.f};
#pragma unroll
  for (int ks = 0; ks < 8; ++ks) {
    int c = ks * 4 + kg4;
    half8 Ka0 = *(const half8*)(Kt0h + (c * 32 + (ml ^ c)) * 8);
    half8 Ka1 = *(const half8*)(Kt0h + (c * 32 + ((16 + ml) ^ c)) * 8);
    S0 = __builtin_amdgcn_mfma_f32_16x16x32_f16(Ka0, Qb[ks], S0, 0, 0, 0);
    S1 = __builtin_amdgcn_mfma_f32_16x16x32_f16(Ka1, Qb[ks], S1, 0, 0, 0);
  }

// Iteration kt: [vmcnt+barrier; stage K(kt+2)->GT; V(kt) half1; QK(kt+1)
// from QB -> T; V(kt) half2; softmax(kt) on SAVED S (|| QK on MFMA pipe);
// exchange; PV(kt); S = T]. QB/GT alternate; kt=127's QK output is unused
// (wraps harmlessly); its gll drains at the epilogue __syncthreads.
#define ITER_BODY(KT, QB, GT)                                                  \
  {                                                                            \
    int kt_ = (KT);                                                            \
    asm volatile("s_waitcnt vmcnt(0)" ::: "memory");                           \
    __builtin_amdgcn_s_barrier();                                              \
    int ktn_ = (kt_ + 2) & 127;                                                \
    _Pragma("unroll")                                                          \
    for (int j = 0; j < 4; ++j)                                                \
      gload_lds16(Kg + (size_t)ktn_ * 1024 + ksrc[j], (GT) + (w * 4 + j) * 64);\
    int4 vr0[4];                                                               \
    _Pragma("unroll")                                                          \
    for (int n = 0; n < 4; ++n)                                                \
      vr0[n] = Vg[(size_t)(vrow + n * 16) * (HW / 8) + kt_ * 4 + kg4];         \
    f32x4 T0 = (f32x4){0.f, 0.f, 0.f, 0.f};                                    \
    f32x4 T1 = (f32x4){0.f, 0.f, 0.f, 0.f};                                    \
    _Pragma("unroll")                                                          \
    for (int ks = 0; ks < 8; ++ks) {                                           \
      int c = ks * 4 + kg4;                                                    \
      half8 Ka0 = *(const half8*)((QB) + (c * 32 + (ml ^ c)) * 8);             \
      half8 Ka1 = *(const half8*)((QB) + (c * 32 + ((16 + ml) ^ c)) * 8);      \
      T0 = __builtin_amdgcn_mfma_f32_16x16x32_f16(Ka0, Qb[ks], T0, 0, 0, 0);   \
      T1 = __builtin_amdgcn_mfma_f32_16x16x32_f16(Ka1, Qb[ks], T1, 0, 0, 0);   \
    }                                                                          \
    int4 vr1[4];                                                               \
    _Pragma("unroll")                                                          \
    for (int n = 0; n < 4; ++n)                                                \
      vr1[n] = Vg[(size_t)(vrow + (n + 4) * 16) * (HW / 8) + kt_ * 4 + kg4];   \
    /* defer-max online softmax on SAVED S (tile kt_) */                       \
    float tm = fmaxf(fmaxf(fmaxf(S0[0], S0[1]), fmaxf(S0[2], S0[3])),          \
                     fmaxf(fmaxf(S1[0], S1[1]), fmaxf(S1[2], S1[3])));         \
    if (__any((int)(tm > mrun + 8.0f))) {                                      \
      float tr = fmaxf(tm, __shfl_xor(tm, 16, 64));                            \
      tr = fmaxf(tr, __shfl_xor(tr, 32, 64));                                  \
      float mn = fmaxf(mrun, tr);                                              \
      float a = __expf(mrun - mn);                                             \
      mrun = mn;                                                               \
      lrun *= a;                                                               \
      float a4[4];                                                             \
      _Pragma("unroll")                                                        \
      for (int r = 0; r < 4; ++r) a4[r] = __shfl(a, kg4 * 4 + r, 16);          \
      _Pragma("unroll")                                                        \
      for (int nt = 0; nt < 8; ++nt)                                           \
        _Pragma("unroll")                                                      \
        for (int r = 0; r < 4; ++r) { accm[nt][r] *= a4[r]; accs[nt][r] *= a4[r]; } \
    }                                                                          \
    _Float16 phv[8];                                                           \
    float rs = 0.f;                                                            \
    _Pragma("unroll")                                                          \
    for (int r = 0; r < 4; ++r) {                                              \
      _Float16 h0 = (_Float16)__expf(S0[r] - mrun);                            \
      _Float16 h1 = (_Float16)__expf(S1[r] - mrun);                            \
      phv[r] = h0; phv[4 + r] = h1;                                            \
      rs += (float)h0 + (float)h1;                                             \
    }                                                                          \
    lrun += rs;                                                                \
    half8 Pa;                                                                  \
    {                                                                          \
      union Hp { _Float16 h[2]; u32 u; };                                      \
      Hp pA0, pA1, pB0, pB1;                                                   \
      pA0.h[0] = phv[0]; pA0.h[1] = phv[1];                                    \
      pA1.h[0] = phv[2]; pA1.h[1] = phv[3];                                    \
      pB0.h[0] = phv[4]; pB0.h[1] = phv[5];                                    \
      pB1.h[0] = phv[6]; pB1.h[1] = phv[7];                                    \
      u32 A0 = pA0.u, A1 = pA1.u, B0 = pB0.u, B1 = pB1.u;                      \
      u32 oA0 = __shfl_xor((int)A0, 16, 64);                                   \
      u32 oA1 = __shfl_xor((int)A1, 16, 64);                                   \
      u32 oB0 = __shfl_xor((int)B0, 16, 64);                                   \
      u32 oB1 = __shfl_xor((int)B1, 16, 64);                                   \
      u32 n0[4], n1[4];                                                        \
      n0[0] = lo ? oA0 : A0; n0[1] = lo ? oA1 : A1;                            \
      n0[2] = lo ? A0 : oA0; n0[3] = lo ? A1 : oA1;                            \
      n1[0] = lo ? oB0 : B0; n1[1] = lo ? oB1 : B1;                            \
      n1[2] = lo ? B0 : oB0; n1[3] = lo ? B1 : oB1;                            \
      union Pu { u32 u[4]; half8 v; } fin;                                     \
      _Pragma("unroll")                                                        \
      for (int i = 0; i < 4; ++i) {                                            \
        u32 s = hi ? n0[i] : n1[i];                                            \
        u32 r2 = __shfl_xor((int)s, 32, 64);                                   \
        fin.u[i] = (hi == lo) ? (hi ? n1[i] : n0[i]) : r2;                     \
      }                                                                        \
      Pa = fin.v;                                                              \
    }                                                                          \
    _Pragma("unroll")                                                          \
    for (int n = 0; n < 8; ++n) {                                              \
      union { int4 i; half8 v; __half2 h2[4]; } bv;                            \
      bv.i = (n < 4) ? vr0[n] : vr1[n - 4];                                    \
      union { half8 v; __half2 h2[4]; } bh, bl;                                \
      _Pragma("unroll")                                                        \
      for (int u = 0; u < 4; ++u) {                                            \
        __half2 hh = __hmul2(bv.h2[u], bv.h2[u]);                              \
        bh.h2[u] = hh;                                                         \
        bl.h2[u] = __hfma2(bv.h2[u], bv.h2[u], __hneg2(hh));                   \
      }                                                                        \
      accm[n] = __builtin_amdgcn_mfma_f32_16x16x32_f16(Pa, bv.v, accm[n], 0, 0, 0); \
      accs[n] = __builtin_amdgcn_mfma_f32_16x16x32_f16(Pa, bh.v, accs[n], 0, 0, 0); \
      accs[n] = __builtin_amdgcn_mfma_f32_16x16x32_f16(Pa, bl.v, accs[n], 0, 0, 0); \
    }                                                                          \
    S0 = T0;                                                                   \
    S1 = T1;                                                                   \
  }

  for (int kt2 = 0; kt2 < 64; ++kt2) {
    ITER_BODY(2 * kt2, Kt1h, smem);             // QK(odd) from buf1; gll->buf0
    ITER_BODY(2 * kt2 + 1, Kt0h, smem + 1024);  // QK(even) from buf0; gll->buf1
  }
#undef ITER_BODY

  // ---- merge l across the 4 kg4 lanes (m already uniform per q) ----
  {
    lrun += __shfl_xor(lrun, 16, 64);
    lrun += __shfl_xor(lrun, 32, 64);
  }
  float invl = 1.0f / lrun;                 // valid for q = ml
  float invl4[4];
#pragma unroll
  for (int r = 0; r < 4; ++r)
    invl4[r] = __shfl(invl, kg4 * 4 + r, 16);  // q = kg4*4 + r (acc row)

  // ---- finalize: fold 1/l; mu and sd per (q, ch) ----
#pragma unroll
  for (int nt = 0; nt < 8; ++nt)
#pragma unroll
    for (int r = 0; r < 4; ++r) {
      float mu = accm[nt][r] * invl4[r];
      float s2 = accs[nt][r] * invl4[r];
      accm[nt][r] = mu;
      accs[nt][r] = sqrtf(fmaxf(s2 - mu * mu, 0.f));
    }

  // ---- epilogue: LDS transpose (8 phases x 32 ch) + content fusion ----
  __syncthreads();
  float* MUL = (float*)smem;        // [32][36] f32
  float* SDL = MUL + 32 * 36;
#pragma unroll 1
  for (int ph2 = 0; ph2 < 8; ++ph2) {
    __syncthreads();
    if (chh == (ph2 >> 2)) {
      int ntb = (ph2 & 3) * 2;
#pragma unroll
      for (int nn = 0; nn < 2; ++nn)
#pragma unroll
        for (int r = 0; r < 4; ++r) {
          int row32 = nn * 16 + ml;
          int ql = qh * 16 + kg4 * 4 + r;
          MUL[row32 * 36 + ql] = accm[ntb + nn][r];
          SDL[row32 * 36 + ql] = accs[ntb + nn][r];
        }
    }
    __syncthreads();
    int qq = (t & 7) * 4;
    int chl = t >> 3;  // 0..31
    int ch = ph2 * 32 + chl;
    float4 mu4 = *(float4*)&MUL[chl * 36 + qq];
    float4 sd4 = *(float4*)&SDL[chl * 36 + qq];
    size_t base = ((size_t)(b * NC) + ch) * HW + q0 + qq;
    float4 c4 = *(const float4*)&content[base];
    float mC = meanC[b * NC + ch];
    float rC = rstdC[b * NC + ch];
    float4 o4;
    o4.x = sd4.x * ((c4.x - mC) * rC) + mu4.x;
    o4.y = sd4.y * ((c4.y - mC) * rC) + mu4.y;
    o4.z = sd4.z * ((c4.z - mC) * rC) + mu4.z;
    o4.w = sd4.w * ((c4.w - mC) * rC) + mu4.w;
    *(float4*)&dout[base] = o4;
    *(float4*)&dout[TEN + base] = mu4;
    *(float4*)&dout[2 * TEN + base] = sd4;
  }
}

// ---------------------------------------------------------------------------
extern "C" void kernel_launch(void* const* d_in, const int* in_sizes, int n_in,
                              void* d_out, int out_size, void* d_ws, size_t ws_size,
                              hipStream_t stream) {
  const float* content = (const float*)d_in[0];
  const float* style   = (const float*)d_in[1];
  const float* Wf = (const float*)d_in[2];
  const float* bf = (const float*)d_in[3];
  const float* Wg = (const float*)d_in[4];
  const float* bg = (const float*)d_in[5];
  const float* Wh = (const float*)d_in[6];
  const float* bh = (const float*)d_in[7];
  char* wsb = (char*)d_ws;
  float* out = (float*)d_out;

  hipLaunchKernelGGL(stats_kernel, dim3(2048), dim3(256), 0, stream,
                     content, style, (float*)wsb);
  hipLaunchKernelGGL(proj_kernel, dim3(32, 4, 12), dim3(256), 0, stream,
                     content, style, Wf, bf, Wg, bg, Wh, bh, wsb);
  hipLaunchKernelGGL(attn_kernel, dim3(512), dim3(256), 0, stream,
                     wsb, content, out);
}

// Round 11
// 607.356 us; speedup vs baseline: 2.6807x; 2.6807x over previous
//
#include <hip/hip_runtime.h>
#include <hip/hip_fp16.h>
#include <math.h>

// Problem constants: B=4, C=256, H=W=64 -> HW=4096
#define HW 4096
#define NC 256
#define NB 4
#define EPSF 1e-5f
#define TEN (NB * HW * NC)  // elements per output tensor = 4194304

typedef _Float16 half8 __attribute__((ext_vector_type(8)));
typedef _Float16 half4v __attribute__((ext_vector_type(4)));
typedef float f32x4 __attribute__((ext_vector_type(4)));
typedef unsigned int u32;

// ws layout (bytes):
//  [0, 16K)   stats f32: meanC[1024], rstdC[1024], meanS[1024], rstdS[1024]
//  QF : f16 [b][pix][256]  (pixel-major)
//  KF : f16 [b][pix][256]  (pixel-major)
//  VF : f16 [b][ch][4096]  (channel-major)
#define STATS_BYTES (4096 * 4)
#define QF_OFF  (STATS_BYTES)
#define KF_OFF  (QF_OFF + TEN * 2)
#define VF_OFF  (KF_OFF + TEN * 2)

// async global->LDS, 16B/lane; LDS dest = wave-uniform base + lane*16
typedef const __attribute__((address_space(1))) void* gas_vp;
typedef __attribute__((address_space(3))) void* las_vp;
__device__ __forceinline__ void gload_lds16(const void* g, void* l) {
  __builtin_amdgcn_global_load_lds((gas_vp)g, (las_vp)l, 16, 0, 0);
}

// ---------------------------------------------------------------------------
// Kernel 1: per-(b,c) mean and rstd for content and style.
// ---------------------------------------------------------------------------
__global__ __launch_bounds__(256) void stats_kernel(
    const float* __restrict__ content, const float* __restrict__ style,
    float* __restrict__ ws) {
  int bc = blockIdx.x;
  int t = threadIdx.x;
  const float* src = (bc < 1024 ? content : style) + (size_t)(bc & 1023) * HW;
  const float4* s4 = (const float4*)src;
  float sum = 0.f, ss = 0.f;
#pragma unroll
  for (int n = 0; n < 4; ++n) {
    float4 v = s4[t + n * 256];
    sum += v.x + v.y + v.z + v.w;
    ss += v.x * v.x + v.y * v.y + v.z * v.z + v.w * v.w;
  }
#pragma unroll
  for (int m = 1; m < 64; m <<= 1) {
    sum += __shfl_xor(sum, m, 64);
    ss += __shfl_xor(ss, m, 64);
  }
  __shared__ float redS[4], redQ[4];
  int w = t >> 6;
  if ((t & 63) == 0) { redS[w] = sum; redQ[w] = ss; }
  __syncthreads();
  if (t == 0) {
    float S = redS[0] + redS[1] + redS[2] + redS[3];
    float Q2 = redQ[0] + redQ[1] + redQ[2] + redQ[3];
    float mean = S * (1.0f / HW);
    float var = (Q2 - S * mean) * (1.0f / (HW - 1));
    float rstd = rsqrtf(var + EPSF);
    float* meanArr = ws + (bc < 1024 ? 0 : 2048);
    float* rstdArr = meanArr + 1024;
    meanArr[bc & 1023] = mean;
    rstdArr[bc & 1023] = rstd;
  }
}

// ---------------------------------------------------------------------------
// Kernel 2: fused normalize + 1x1 conv; f16 outputs (V only; V^2 in attn).
// ---------------------------------------------------------------------------
__global__ __launch_bounds__(256) void proj_kernel(
    const float* __restrict__ content, const float* __restrict__ style,
    const float* __restrict__ Wf, const float* __restrict__ bf,
    const float* __restrict__ Wg, const float* __restrict__ bg,
    const float* __restrict__ Wh, const float* __restrict__ bh,
    char* __restrict__ wsb) {
  float* ws = (float*)wsb;
  int pt = blockIdx.x;
  int ot = blockIdx.y;
  int z = blockIdx.z;
  int tensor = z >> 2, b = z & 3;

  const float* X; const float* Wm; const float* bias;
  const float* meanA = nullptr; const float* rstdA = nullptr;
  if (tensor == 0)      { X = content; Wm = Wf; bias = bf; meanA = ws;        rstdA = ws + 1024; }
  else if (tensor == 1) { X = style;   Wm = Wg; bias = bg; meanA = ws + 2048; rstdA = ws + 3072; }
  else                  { X = style;   Wm = Wh; bias = bh; }

  __shared__ float Xs[32 * 132];
  __shared__ float Wt[32 * 68];

  int t = threadIdx.x;
  int p0 = pt * 128, o0 = ot * 64;
  int o_base = (t >> 4) * 4;
  int p_base = (t & 15) * 8;

  float bb[4];
  { float4 b4 = *(const float4*)&bias[o0 + o_base];
    bb[0] = b4.x; bb[1] = b4.y; bb[2] = b4.z; bb[3] = b4.w; }
  float acc[4][8];
#pragma unroll
  for (int oo = 0; oo < 4; ++oo)
#pragma unroll
    for (int pp = 0; pp < 8; ++pp) acc[oo][pp] = bb[oo];

  const float4* X4 = (const float4*)X;
  const float4* Wm4 = (const float4*)Wm;

  for (int kc = 0; kc < 8; ++kc) {
    int k0 = kc * 32;
    __syncthreads();
#pragma unroll
    for (int n = 0; n < 4; ++n) {
      int f = t + n * 256;
      int kk = f >> 5, p4 = f & 31;
      float4 v = X4[(size_t)(b * NC + k0 + kk) * (HW / 4) + (p0 / 4) + p4];
      if (tensor < 2) {
        float mC = meanA[b * NC + k0 + kk], rC = rstdA[b * NC + k0 + kk];
        v.x = (v.x - mC) * rC; v.y = (v.y - mC) * rC;
        v.z = (v.z - mC) * rC; v.w = (v.w - mC) * rC;
      }
      *(float4*)&Xs[kk * 132 + p4 * 4] = v;
    }
#pragma unroll
    for (int n = 0; n < 2; ++n) {
      int f = t + n * 256;
      int o = f >> 3, k4 = f & 7;
      float4 v = Wm4[(size_t)(o0 + o) * (NC / 4) + kc * 8 + k4];
      Wt[(k4 * 4 + 0) * 68 + o] = v.x;
      Wt[(k4 * 4 + 1) * 68 + o] = v.y;
      Wt[(k4 * 4 + 2) * 68 + o] = v.z;
      Wt[(k4 * 4 + 3) * 68 + o] = v.w;
    }
    __syncthreads();
#pragma unroll
    for (int kk = 0; kk < 32; ++kk) {
      float4 w4 = *(float4*)&Wt[kk * 68 + o_base];
      float4 xa = *(float4*)&Xs[kk * 132 + p_base];
      float4 xb = *(float4*)&Xs[kk * 132 + p_base + 4];
      float wv[4] = {w4.x, w4.y, w4.z, w4.w};
      float xv[8] = {xa.x, xa.y, xa.z, xa.w, xb.x, xb.y, xb.z, xb.w};
#pragma unroll
      for (int oo = 0; oo < 4; ++oo)
#pragma unroll
        for (int pp = 0; pp < 8; ++pp)
          acc[oo][pp] = fmaf(wv[oo], xv[pp], acc[oo][pp]);
    }
  }

  if (tensor < 2) {
    _Float16* dst = (_Float16*)(wsb + (tensor == 0 ? QF_OFF : KF_OFF));
#pragma unroll
    for (int pp = 0; pp < 8; ++pp) {
      half4v h;
      h[0] = (_Float16)acc[0][pp]; h[1] = (_Float16)acc[1][pp];
      h[2] = (_Float16)acc[2][pp]; h[3] = (_Float16)acc[3][pp];
      *(half4v*)&dst[((size_t)(b * HW) + p0 + p_base + pp) * 256 + o0 + o_base] = h;
    }
  } else {
    _Float16* dV = (_Float16*)(wsb + VF_OFF);
#pragma unroll
    for (int oo = 0; oo < 4; ++oo) {
      int ch = o0 + o_base + oo;
      half8 hv;
#pragma unroll
      for (int pp = 0; pp < 8; ++pp) hv[pp] = (_Float16)acc[oo][pp];
      size_t base = ((size_t)(b * NC) + ch) * HW + p0 + p_base;
      *(half8*)&dV[base] = hv;
    }
  }
}

// ---------------------------------------------------------------------------
// Kernel 3: flash attention, single pass, defer-max, S-pipelined.
// ROUND-11: identical to r10 except __launch_bounds__(256,2). r10's
// pipeline was correct (absmax ok) but spilled: the ,3 bound caps ~170
// regs; r8 used 148 and the pipeline adds T0/T1 (+8) + vr0/vr1 held live
// across softmax (+32) -> FETCH/WRITE exploded to 2.4GB/1.4GB scratch
// traffic. The ,3 cap bought NOTHING: occupancy is grid-limited (512
// blocks = 2 blocks/CU = 8 waves/CU) — identical at ,2. With cap ~256
// the ~185-reg pipeline fits with slack; this is the clean A/B of the
// S-pipeline (softmax(t) VALU work under QK(t+1) MFMAs, m114 co-issue).
// Numerics BIT-IDENTICAL to r8. All r8 pieces verbatim otherwise.
// ---------------------------------------------------------------------------
__global__ __launch_bounds__(256, 2) void attn_kernel(
    char* __restrict__ wsb, const float* __restrict__ content,
    float* __restrict__ dout) {
  const _Float16* Qf = (const _Float16*)(wsb + QF_OFF);
  const _Float16* Kf = (const _Float16*)(wsb + KF_OFF);
  const _Float16* Vf = (const _Float16*)(wsb + VF_OFF);
  const float* meanC = (const float*)wsb;
  const float* rstdC = meanC + 1024;

  int raw = blockIdx.x;                      // 0..511
  int xcd = raw & 7;
  int b = xcd >> 1;
  int qt = ((raw >> 3) << 1) | (xcd & 1);    // 0..127, bijective
  int q0 = qt * 32;

  int t = threadIdx.x;
  int lane = t & 63;
  int w = t >> 6;     // 0..3
  int qh = w >> 1;    // 0..1: which 16 queries
  int chh = w & 1;    // 0..1: which 128 channels
  int ml = lane & 15;
  int kg4 = lane >> 4;
  int lo = kg4 & 1, hi = kg4 >> 1;

  __shared__ int4 smem[2048];                // 32 KB: two 16 KB K buffers
  _Float16* Kt0h = (_Float16*)smem;
  _Float16* Kt1h = (_Float16*)(smem + 1024);

  // ---- Q B-frags: 16 queries x 256 ch per wave (32 VGPRs) ----
  half8 Qb[8];
#pragma unroll
  for (int ks = 0; ks < 8; ++ks) {
    size_t off = ((size_t)(b * HW) + q0 + qh * 16 + ml) * 256 + ks * 32 + kg4 * 8;
    Qb[ks] = *(const half8*)(Qf + off);
  }

  f32x4 accm[8], accs[8];
#pragma unroll
  for (int nt = 0; nt < 8; ++nt) {
    accm[nt] = (f32x4){0.f, 0.f, 0.f, 0.f};
    accs[nt] = (f32x4){0.f, 0.f, 0.f, 0.f};
  }
  float mrun = -INFINITY;   // per-lane state for q = ml (uniform across kg4)
  float lrun = 0.f;         // per-lane partial (this lane's 8 key slots)

  const int4* Kg = (const int4*)(Kf + (size_t)b * HW * 256);  // [key][32 gran]
  const int4* Vg = (const int4*)(Vf + (size_t)b * NC * HW);   // [ch][512 gran]
  int vrow = chh * 128 + ml;

  // K staging source pre-swizzle (r4-r8-proven): LDS slot s = c*32+(key^c);
  // chunk n=w*4+j covers slots n*64+lane; src gran = (l31^c)*32+c.
  int ksrc[4];
  {
    int l5 = lane >> 5;
    int l31 = lane & 31;
#pragma unroll
    for (int j = 0; j < 4; ++j) {
      int c = (w * 4 + j) * 2 + l5;
      ksrc[j] = (l31 ^ c) * 32 + c;  // + kt*1024
    }
  }

  // ---- prologue: K(0)->buf0 (waited), K(1)->buf1 (in flight), QK(0) ----
#pragma unroll
  for (int j = 0; j < 4; ++j)
    gload_lds16(Kg + (size_t)ksrc[j], smem + (w * 4 + j) * 64);
  asm volatile("s_waitcnt vmcnt(0)" ::: "memory");
  __builtin_amdgcn_s_barrier();
#pragma unroll
  for (int j = 0; j < 4; ++j)
    gload_lds16(Kg + (size_t)(1024 + ksrc[j]), smem + 1024 + (w * 4 + j) * 64);

  f32x4 S0 = (f32x4){0.f, 0.f, 0.f, 0.f};
  f32x4 S1 = (f32x4){0.f, 0.f, 0.f, 0.f};
#pragma unroll
  for (int ks = 0; ks < 8; ++ks) {
    int c = ks * 4 + kg4;
    half8 Ka0 = *(const half8*)(Kt0h + (c * 32 + (ml ^ c)) * 8);
    half8 Ka1 = *(const half8*)(Kt0h + (c * 32 + ((16 + ml) ^ c)) * 8);
    S0 = __builtin_amdgcn_mfma_f32_16x16x32_f16(Ka0, Qb[ks], S0, 0, 0, 0);
    S1 = __builtin_amdgcn_mfma_f32_16x16x32_f16(Ka1, Qb[ks], S1, 0, 0, 0);
  }

// Iteration kt: [vmcnt+barrier; stage K(kt+2)->GT; V(kt) half1; QK(kt+1)
// from QB -> T; V(kt) half2; softmax(kt) on SAVED S (|| QK on MFMA pipe);
// exchange; PV(kt); S = T]. QB/GT alternate; kt=127's QK output is unused
// (wraps harmlessly); its gll drains at the epilogue __syncthreads.
#define ITER_BODY(KT, QB, GT)                                                  \
  {                                                                            \
    int kt_ = (KT);                                                            \
    asm volatile("s_waitcnt vmcnt(0)" ::: "memory");                           \
    __builtin_amdgcn_s_barrier();                                              \
    int ktn_ = (kt_ + 2) & 127;                                                \
    _Pragma("unroll")                                                          \
    for (int j = 0; j < 4; ++j)                                                \
      gload_lds16(Kg + (size_t)ktn_ * 1024 + ksrc[j], (GT) + (w * 4 + j) * 64);\
    int4 vr0[4];                                                               \
    _Pragma("unroll")                                                          \
    for (int n = 0; n < 4; ++n)                                                \
      vr0[n] = Vg[(size_t)(vrow + n * 16) * (HW / 8) + kt_ * 4 + kg4];         \
    f32x4 T0 = (f32x4){0.f, 0.f, 0.f, 0.f};                                    \
    f32x4 T1 = (f32x4){0.f, 0.f, 0.f, 0.f};                                    \
    _Pragma("unroll")                                                          \
    for (int ks = 0; ks < 8; ++ks) {                                           \
      int c = ks * 4 + kg4;                                                    \
      half8 Ka0 = *(const half8*)((QB) + (c * 32 + (ml ^ c)) * 8);             \
      half8 Ka1 = *(const half8*)((QB) + (c * 32 + ((16 + ml) ^ c)) * 8);      \
      T0 = __builtin_amdgcn_mfma_f32_16x16x32_f16(Ka0, Qb[ks], T0, 0, 0, 0);   \
      T1 = __builtin_amdgcn_mfma_f32_16x16x32_f16(Ka1, Qb[ks], T1, 0, 0, 0);   \
    }                                                                          \
    int4 vr1[4];                                                               \
    _Pragma("unroll")                                                          \
    for (int n = 0; n < 4; ++n)                                                \
      vr1[n] = Vg[(size_t)(vrow + (n + 4) * 16) * (HW / 8) + kt_ * 4 + kg4];   \
    /* defer-max online softmax on SAVED S (tile kt_) */                       \
    float tm = fmaxf(fmaxf(fmaxf(S0[0], S0[1]), fmaxf(S0[2], S0[3])),          \
                     fmaxf(fmaxf(S1[0], S1[1]), fmaxf(S1[2], S1[3])));         \
    if (__any((int)(tm > mrun + 8.0f))) {                                      \
      float tr = fmaxf(tm, __shfl_xor(tm, 16, 64));                            \
      tr = fmaxf(tr, __shfl_xor(tr, 32, 64));                                  \
      float mn = fmaxf(mrun, tr);                                              \
      float a = __expf(mrun - mn);                                             \
      mrun = mn;                                                               \
      lrun *= a;                                                               \
      float a4[4];                                                             \
      _Pragma("unroll")                                                        \
      for (int r = 0; r < 4; ++r) a4[r] = __shfl(a, kg4 * 4 + r, 16);          \
      _Pragma("unroll")                                                        \
      for (int nt = 0; nt < 8; ++nt)                                           \
        _Pragma("unroll")                                                      \
        for (int r = 0; r < 4; ++r) { accm[nt][r] *= a4[r]; accs[nt][r] *= a4[r]; } \
    }                                                                          \
    _Float16 phv[8];                                                           \
    float rs = 0.f;                                                            \
    _Pragma("unroll")                                                          \
    for (int r = 0; r < 4; ++r) {                                              \
      _Float16 h0 = (_Float16)__expf(S0[r] - mrun);                            \
      _Float16 h1 = (_Float16)__expf(S1[r] - mrun);                            \
      phv[r] = h0; phv[4 + r] = h1;                                            \
      rs += (float)h0 + (float)h1;                                             \
    }                                                                          \
    lrun += rs;                                                                \
    half8 Pa;                                                                  \
    {                                                                          \
      union Hp { _Float16 h[2]; u32 u; };                                      \
      Hp pA0, pA1, pB0, pB1;                                                   \
      pA0.h[0] = phv[0]; pA0.h[1] = phv[1];                                    \
      pA1.h[0] = phv[2]; pA1.h[1] = phv[3];                                    \
      pB0.h[0] = phv[4]; pB0.h[1] = phv[5];                                    \
      pB1.h[0] = phv[6]; pB1.h[1] = phv[7];                                    \
      u32 A0 = pA0.u, A1 = pA1.u, B0 = pB0.u, B1 = pB1.u;                      \
      u32 oA0 = __shfl_xor((int)A0, 16, 64);                                   \
      u32 oA1 = __shfl_xor((int)A1, 16, 64);                                   \
      u32 oB0 = __shfl_xor((int)B0, 16, 64);                                   \
      u32 oB1 = __shfl_xor((int)B1, 16, 64);                                   \
      u32 n0[4], n1[4];                                                        \
      n0[0] = lo ? oA0 : A0; n0[1] = lo ? oA1 : A1;                            \
      n0[2] = lo ? A0 : oA0; n0[3] = lo ? A1 : oA1;                            \
      n1[0] = lo ? oB0 : B0; n1[1] = lo ? oB1 : B1;                            \
      n1[2] = lo ? B0 : oB0; n1[3] = lo ? B1 : oB1;                            \
      union Pu { u32 u[4]; half8 v; } fin;                                     \
      _Pragma("unroll")                                                        \
      for (int i = 0; i < 4; ++i) {                                            \
        u32 s = hi ? n0[i] : n1[i];                                            \
        u32 r2 = __shfl_xor((int)s, 32, 64);                                   \
        fin.u[i] = (hi == lo) ? (hi ? n1[i] : n0[i]) : r2;                     \
      }                                                                        \
      Pa = fin.v;                                                              \
    }                                                                          \
    _Pragma("unroll")                                                          \
    for (int n = 0; n < 8; ++n) {                                              \
      union { int4 i; half8 v; __half2 h2[4]; } bv;                            \
      bv.i = (n < 4) ? vr0[n] : vr1[n - 4];                                    \
      union { half8 v; __half2 h2[4]; } bh, bl;                                \
      _Pragma("unroll")                                                        \
      for (int u = 0; u < 4; ++u) {                                            \
        __half2 hh = __hmul2(bv.h2[u], bv.h2[u]);                              \
        bh.h2[u] = hh;                                                         \
        bl.h2[u] = __hfma2(bv.h2[u], bv.h2[u], __hneg2(hh));                   \
      }                                                                        \
      accm[n] = __builtin_amdgcn_mfma_f32_16x16x32_f16(Pa, bv.v, accm[n], 0, 0, 0); \
      accs[n] = __builtin_amdgcn_mfma_f32_16x16x32_f16(Pa, bh.v, accs[n], 0, 0, 0); \
      accs[n] = __builtin_amdgcn_mfma_f32_16x16x32_f16(Pa, bl.v, accs[n], 0, 0, 0); \
    }                                                                          \
    S0 = T0;                                                                   \
    S1 = T1;                                                                   \
  }

  for (int kt2 = 0; kt2 < 64; ++kt2) {
    ITER_BODY(2 * kt2, Kt1h, smem);             // QK(odd) from buf1; gll->buf0
    ITER_BODY(2 * kt2 + 1, Kt0h, smem + 1024);  // QK(even) from buf0; gll->buf1
  }
#undef ITER_BODY

  // ---- merge l across the 4 kg4 lanes (m already uniform per q) ----
  {
    lrun += __shfl_xor(lrun, 16, 64);
    lrun += __shfl_xor(lrun, 32, 64);
  }
  float invl = 1.0f / lrun;                 // valid for q = ml
  float invl4[4];
#pragma unroll
  for (int r = 0; r < 4; ++r)
    invl4[r] = __shfl(invl, kg4 * 4 + r, 16);  // q = kg4*4 + r (acc row)

  // ---- finalize: fold 1/l; mu and sd per (q, ch) ----
#pragma unroll
  for (int nt = 0; nt < 8; ++nt)
#pragma unroll
    for (int r = 0; r < 4; ++r) {
      float mu = accm[nt][r] * invl4[r];
      float s2 = accs[nt][r] * invl4[r];
      accm[nt][r] = mu;
      accs[nt][r] = sqrtf(fmaxf(s2 - mu * mu, 0.f));
    }

  // ---- epilogue: LDS transpose (8 phases x 32 ch) + content fusion ----
  __syncthreads();
  float* MUL = (float*)smem;        // [32][36] f32
  float* SDL = MUL + 32 * 36;
#pragma unroll 1
  for (int ph2 = 0; ph2 < 8; ++ph2) {
    __syncthreads();
    if (chh == (ph2 >> 2)) {
      int ntb = (ph2 & 3) * 2;
#pragma unroll
      for (int nn = 0; nn < 2; ++nn)
#pragma unroll
        for (int r = 0; r < 4; ++r) {
          int row32 = nn * 16 + ml;
          int ql = qh * 16 + kg4 * 4 + r;
          MUL[row32 * 36 + ql] = accm[ntb + nn][r];
          SDL[row32 * 36 + ql] = accs[ntb + nn][r];
        }
    }
    __syncthreads();
    int qq = (t & 7) * 4;
    int chl = t >> 3;  // 0..31
    int ch = ph2 * 32 + chl;
    float4 mu4 = *(float4*)&MUL[chl * 36 + qq];
    float4 sd4 = *(float4*)&SDL[chl * 36 + qq];
    size_t base = ((size_t)(b * NC) + ch) * HW + q0 + qq;
    float4 c4 = *(const float4*)&content[base];
    float mC = meanC[b * NC + ch];
    float rC = rstdC[b * NC + ch];
    float4 o4;
    o4.x = sd4.x * ((c4.x - mC) * rC) + mu4.x;
    o4.y = sd4.y * ((c4.y - mC) * rC) + mu4.y;
    o4.z = sd4.z * ((c4.z - mC) * rC) + mu4.z;
    o4.w = sd4.w * ((c4.w - mC) * rC) + mu4.w;
    *(float4*)&dout[base] = o4;
    *(float4*)&dout[TEN + base] = mu4;
    *(float4*)&dout[2 * TEN + base] = sd4;
  }
}

// ---------------------------------------------------------------------------
extern "C" void kernel_launch(void* const* d_in, const int* in_sizes, int n_in,
                              void* d_out, int out_size, void* d_ws, size_t ws_size,
                              hipStream_t stream) {
  const float* content = (const float*)d_in[0];
  const float* style   = (const float*)d_in[1];
  const float* Wf = (const float*)d_in[2];
  const float* bf = (const float*)d_in[3];
  const float* Wg = (const float*)d_in[4];
  const float* bg = (const float*)d_in[5];
  const float* Wh = (const float*)d_in[6];
  const float* bh = (const float*)d_in[7];
  char* wsb = (char*)d_ws;
  float* out = (float*)d_out;

  hipLaunchKernelGGL(stats_kernel, dim3(2048), dim3(256), 0, stream,
                     content, style, (float*)wsb);
  hipLaunchKernelGGL(proj_kernel, dim3(32, 4, 12), dim3(256), 0, stream,
                     content, style, Wf, bf, Wg, bg, Wh, bh, wsb);
  hipLaunchKernelGGL(attn_kernel, dim3(512), dim3(256), 0, stream,
                     wsb, content, out);
}